// Round 15
// baseline (4764.459 us; speedup 1.0000x reference)
//
#include <hip/hip_runtime.h>

// ---------------------------------------------------------------------------
// RNN attention decoder (GRU x2 + general attention + generator), MI355X.
// Round 15 (base = round 14):
//   - loop: out_red FUSED into the Wc GEMM via deterministic last-finisher
//     (release fence + device-scope atomic counter per tile; last of 16
//     K-split blocks sums planes 0..15 in fixed order -> bit-identical).
//     6 -> 5 launches/step.  Fence/atomic protocol proven bit-correct on
//     this chip by round-12's persistent-barrier run.
//   - generator: unchanged (time-chunked tiles + gload_lds staging).
// Precision (verified round 6): split-bf16 hi/lo 3-term K-concat on all
// recurrence/attention GEMMs; plain bf16 generator.
// ---------------------------------------------------------------------------

using u16 = unsigned short;
typedef __attribute__((ext_vector_type(4))) float f32x4;
typedef __attribute__((ext_vector_type(4))) u16 u16x4;
typedef __attribute__((ext_vector_type(8))) u16 u16x8;
typedef __attribute__((ext_vector_type(8))) __bf16 bf16x8;

#define DEVFN static __device__ __forceinline__

DEVFN u16 f2bf(float f) {
  unsigned u = __float_as_uint(f);
  return (u16)((u + 0x7FFFu + ((u >> 16) & 1u)) >> 16);
}
DEVFN float bf2f(u16 h) { return __uint_as_float(((unsigned)h) << 16); }
DEVFN float sigm(float x) { return 1.0f / (1.0f + expf(-x)); }
DEVFN float gru_gate(float ir, float iz, float inn,
                     float hr, float hz, float hn, float hprev) {
  float r = sigm(ir + hr);
  float z = sigm(iz + hz);
  float n = tanhf(inn + r * hn);
  return (1.0f - z) * n + z * hprev;
}

// async global->LDS stage of one [ROWS][64] bf16 tile with XOR-swizzle.
// LDS layout: LDS[row*64 + x*8] = global[row, (x^(row&7))*8 ..+8)
template <int ROWS>
DEVFN void stage_tile(const u16* __restrict__ G, int ldg, int kt, u16* lds,
                      int tid) {
  constexpr int IT = (ROWS * 8) / 256;  // 16B chunks per thread
  const int wvbase = tid & ~63;
#pragma unroll
  for (int i = 0; i < IT; ++i) {
    const int chunk = i * 256 + tid;
    const int row = chunk >> 3, c8 = chunk & 7;
    const int cs = c8 ^ (row & 7);
    const u16* src = G + (size_t)row * ldg + (kt * 64 + cs * 8);
    u16* dst = lds + (size_t)(i * 256 + wvbase) * 8;  // wave-uniform base
    __builtin_amdgcn_global_load_lds(
        (const __attribute__((address_space(1))) void*)src,
        (__attribute__((address_space(3))) void*)dst, 16, 0, 0);
  }
}

// ---------------------------------------------------------------------------
// Full-K GEMM C = A * B^T (prologue / generator).
// mode 0: mt-major (mt = bx/Ntiles).  mode 2: chunked 25-nt x 32-mt.
// ---------------------------------------------------------------------------
struct GemmB3 {
  const u16* A[3];
  const u16* B[3];
  void* C[3];
  int ldb[3];
};

template <int BM, int BN, int OUTMODE, bool BIAS>
__global__ __launch_bounds__(256) void gemm_bt(
    GemmB3 args, int lda, int ldc, int Ntiles, int K,
    const float* __restrict__ bias, int mode) {
  constexpr int MF = BM / 32;
  constexpr int NF = BN / 32;
  __shared__ alignas(16) u16 lsA[BM * 64];
  __shared__ alignas(16) u16 lsB[BN * 64];

  const int g = blockIdx.y;
  const int bx = blockIdx.x;
  int mt, nt;
  if (mode == 2) {
    const int c = bx / 800;  // chunk of 25 nt-panels
    const int r = bx - c * 800;
    mt = r & 31;
    nt = c * 25 + (r >> 5);
  } else {
    mt = bx / Ntiles;
    nt = bx - mt * Ntiles;
  }
  const int tid = threadIdx.x;
  const int lane = tid & 63;
  const int wv = tid >> 6;
  const int wr = wv >> 1, wc = wv & 1;
  const int l15 = lane & 15, l4 = lane >> 4;
  const int ldb = args.ldb[g];
  const u16* __restrict__ Ag = args.A[g] + (size_t)mt * BM * lda;
  const u16* __restrict__ Bg = args.B[g] + (size_t)nt * BN * ldb;

  f32x4 acc[MF][NF];
#pragma unroll
  for (int m = 0; m < MF; ++m)
#pragma unroll
    for (int n = 0; n < NF; ++n) acc[m][n] = f32x4{0.f, 0.f, 0.f, 0.f};

  const int KT = K >> 6;
  for (int kt = 0; kt < KT; ++kt) {
    stage_tile<BM>(Ag, lda, kt, lsA, tid);
    stage_tile<BN>(Bg, ldb, kt, lsB, tid);
    __syncthreads();
#pragma unroll
    for (int ks = 0; ks < 2; ++ks) {
      bf16x8 av[MF], bv[NF];
#pragma unroll
      for (int m = 0; m < MF; ++m) {
        const int row = wr * (BM / 2) + m * 16 + l15;
        const int cc = (ks * 4 + l4) ^ (row & 7);
        av[m] = *reinterpret_cast<const bf16x8*>(lsA + row * 64 + cc * 8);
      }
#pragma unroll
      for (int n = 0; n < NF; ++n) {
        const int row = wc * (BN / 2) + n * 16 + l15;
        const int cc = (ks * 4 + l4) ^ (row & 7);
        bv[n] = *reinterpret_cast<const bf16x8*>(lsB + row * 64 + cc * 8);
      }
#pragma unroll
      for (int m = 0; m < MF; ++m)
#pragma unroll
        for (int n = 0; n < NF; ++n)
          acc[m][n] = __builtin_amdgcn_mfma_f32_16x16x32_bf16(
              av[m], bv[n], acc[m][n], 0, 0, 0);
    }
    __syncthreads();
  }

#pragma unroll
  for (int m = 0; m < MF; ++m) {
    const int grow = mt * BM + wr * (BM / 2) + m * 16 + l4 * 4;
#pragma unroll
    for (int n = 0; n < NF; ++n) {
      const int gcol = nt * BN + wc * (BN / 2) + n * 16 + l15;
      const float bsv = BIAS ? bias[gcol] : 0.f;
#pragma unroll
      for (int j = 0; j < 4; ++j) {
        const float v = acc[m][n][j] + bsv;
        const size_t idx = (size_t)(grow + j) * ldc + gcol;
        if constexpr (OUTMODE == 0) {
          ((float*)args.C[g])[idx] = v;
        } else {
          ((u16*)args.C[g])[idx] = f2bf(v);
        }
      }
    }
  }
}

// ---------------------------------------------------------------------------
// K-split partial GEMM: C[g][plane=ks] = A * B^T over K-slice ks.
// ---------------------------------------------------------------------------
struct GemmP {
  const u16* A[3];
  const u16* B[3];
  float* C[3];
};

template <int BM, int BN>
__global__ __launch_bounds__(256) void gemm_part(
    GemmP args, int lda, int ldb, int N, int Ntiles, int KS, int nkt,
    int Mrows) {
  constexpr int MF = BM / 32;
  constexpr int NF = BN / 32;
  __shared__ alignas(16) u16 lsA[BM * 64];
  __shared__ alignas(16) u16 lsB[BN * 64];

  const int g = blockIdx.y;
  const int bx = blockIdx.x;
  const int tile = bx / KS;
  const int ks = bx - tile * KS;
  const int mt = tile / Ntiles;
  const int nt = tile - mt * Ntiles;
  const int tid = threadIdx.x;
  const int lane = tid & 63;
  const int wv = tid >> 6;
  const int wr = wv >> 1, wc = wv & 1;
  const int l15 = lane & 15, l4 = lane >> 4;
  const u16* __restrict__ Ag = args.A[g] + (size_t)mt * BM * lda;
  const u16* __restrict__ Bg = args.B[g] + (size_t)nt * BN * ldb;
  float* __restrict__ Cg =
      args.C[g] + (size_t)ks * Mrows * N + (size_t)mt * BM * N;

  f32x4 acc[MF][NF];
#pragma unroll
  for (int m = 0; m < MF; ++m)
#pragma unroll
    for (int n = 0; n < NF; ++n) acc[m][n] = f32x4{0.f, 0.f, 0.f, 0.f};

  const int kt0 = ks * nkt;
  for (int kk = 0; kk < nkt; ++kk) {
    const int kt = kt0 + kk;
    stage_tile<BM>(Ag, lda, kt, lsA, tid);
    stage_tile<BN>(Bg, ldb, kt, lsB, tid);
    __syncthreads();
#pragma unroll
    for (int k2 = 0; k2 < 2; ++k2) {
      bf16x8 av[MF], bv[NF];
#pragma unroll
      for (int m = 0; m < MF; ++m) {
        const int row = wr * (BM / 2) + m * 16 + l15;
        const int cc = (k2 * 4 + l4) ^ (row & 7);
        av[m] = *reinterpret_cast<const bf16x8*>(lsA + row * 64 + cc * 8);
      }
#pragma unroll
      for (int n = 0; n < NF; ++n) {
        const int row = wc * (BN / 2) + n * 16 + l15;
        const int cc = (k2 * 4 + l4) ^ (row & 7);
        bv[n] = *reinterpret_cast<const bf16x8*>(lsB + row * 64 + cc * 8);
      }
#pragma unroll
      for (int m = 0; m < MF; ++m)
#pragma unroll
        for (int n = 0; n < NF; ++n)
          acc[m][n] = __builtin_amdgcn_mfma_f32_16x16x32_bf16(
              av[m], bv[n], acc[m][n], 0, 0, 0);
    }
    __syncthreads();
  }

#pragma unroll
  for (int m = 0; m < MF; ++m) {
    const int row = wr * (BM / 2) + m * 16 + l4 * 4;
#pragma unroll
    for (int n = 0; n < NF; ++n) {
      const int col = nt * BN + wc * (BN / 2) + n * 16 + l15;
#pragma unroll
      for (int j = 0; j < 4; ++j)
        Cg[(size_t)(row + j) * N + col] = acc[m][n][j];
    }
  }
}

// ---------------------------------------------------------------------------
// Wc GEMM (K-split 16, tiles 2x16 of 64x64) with FUSED out-reduction:
// the last of the 16 K-split blocks per tile sums planes 0..15 (fixed
// order -> bit-identical to the old out_red), applies tanh, and writes
// outf / outall[t] / out3 triple for its 64x64 tile.
// ---------------------------------------------------------------------------
__global__ __launch_bounds__(256) void gemm_wc_fused(
    const u16* __restrict__ cat3, const u16* __restrict__ Wc3,
    float* __restrict__ Wcpart, unsigned* __restrict__ cnt,
    float* __restrict__ outf, u16* __restrict__ outall_t,
    u16* __restrict__ out3) {
  __shared__ alignas(16) u16 lsA[64 * 64];
  __shared__ alignas(16) u16 lsB[64 * 64];
  __shared__ unsigned lastflag;
  const int bx = blockIdx.x;  // 512 = 32 tiles * 16 ks
  const int tile = bx >> 4, ks = bx & 15;
  const int mt = tile >> 4, nt = tile & 15;
  const int tid = threadIdx.x;
  const int lane = tid & 63;
  const int wv = tid >> 6;
  const int wr = wv >> 1, wc = wv & 1;
  const int l15 = lane & 15, l4 = lane >> 4;
  const u16* __restrict__ Ag = cat3 + (size_t)mt * 64 * 6144;
  const u16* __restrict__ Bg = Wc3 + (size_t)nt * 64 * 6144;
  float* __restrict__ Cg =
      Wcpart + (size_t)ks * 131072 + (size_t)mt * 64 * 1024;

  f32x4 acc[2][2];
#pragma unroll
  for (int m = 0; m < 2; ++m)
#pragma unroll
    for (int n = 0; n < 2; ++n) acc[m][n] = f32x4{0.f, 0.f, 0.f, 0.f};

  const int kt0 = ks * 6;
  for (int kk = 0; kk < 6; ++kk) {
    const int kt = kt0 + kk;
    stage_tile<64>(Ag, 6144, kt, lsA, tid);
    stage_tile<64>(Bg, 6144, kt, lsB, tid);
    __syncthreads();
#pragma unroll
    for (int k2 = 0; k2 < 2; ++k2) {
      bf16x8 av[2], bv[2];
#pragma unroll
      for (int m = 0; m < 2; ++m) {
        const int row = wr * 32 + m * 16 + l15;
        const int cc = (k2 * 4 + l4) ^ (row & 7);
        av[m] = *reinterpret_cast<const bf16x8*>(lsA + row * 64 + cc * 8);
      }
#pragma unroll
      for (int n = 0; n < 2; ++n) {
        const int row = wc * 32 + n * 16 + l15;
        const int cc = (k2 * 4 + l4) ^ (row & 7);
        bv[n] = *reinterpret_cast<const bf16x8*>(lsB + row * 64 + cc * 8);
      }
#pragma unroll
      for (int m = 0; m < 2; ++m)
#pragma unroll
        for (int n = 0; n < 2; ++n)
          acc[m][n] = __builtin_amdgcn_mfma_f32_16x16x32_bf16(
              av[m], bv[n], acc[m][n], 0, 0, 0);
    }
    __syncthreads();
  }

#pragma unroll
  for (int m = 0; m < 2; ++m) {
    const int row = wr * 32 + m * 16 + l4 * 4;
#pragma unroll
    for (int n = 0; n < 2; ++n) {
      const int col = nt * 64 + wc * 32 + n * 16 + l15;
#pragma unroll
      for (int j = 0; j < 4; ++j)
        Cg[(size_t)(row + j) * 1024 + col] = acc[m][n][j];
    }
  }

  // completion protocol (fence+atomic pattern proven bit-correct in r12)
  __syncthreads();
  if (tid == 0) {
    __threadfence();  // release: writeback XCD L2 (all block stores)
    lastflag = (__hip_atomic_fetch_add(cnt + tile, 1u, __ATOMIC_ACQ_REL,
                                       __HIP_MEMORY_SCOPE_AGENT) == 15u);
  }
  __syncthreads();
  if (lastflag) {
    if (tid == 0) __threadfence();  // acquire: invalidate caches
    __syncthreads();
    // out-reduction for rows [mt*64, +64), cols [nt*64, +64)
    const int lr = tid >> 2;        // 0..63
    const int lc = (tid & 3) * 16;  // 0,16,32,48
    const int b = mt * 64 + lr;
    u16* d3 = out3 + (size_t)b * 3072;
#pragma unroll
    for (int q = 0; q < 4; ++q) {
      const int c = nt * 64 + lc + q * 4;
      f32x4 v = {0.f, 0.f, 0.f, 0.f};
#pragma unroll
      for (int p2 = 0; p2 < 16; ++p2)
        v += *(const f32x4*)(Wcpart + (size_t)p2 * 131072 +
                             (size_t)b * 1024 + c);
      u16x4 ob;
#pragma unroll
      for (int j = 0; j < 4; ++j) {
        const float o = tanhf(v[j]);
        outf[(size_t)b * 1024 + c + j] = o;
        const u16 hb = f2bf(o);
        const u16 lb = f2bf(o - bf2f(hb));
        ob[j] = hb;
        d3[c + j] = hb;
        d3[1024 + c + j] = lb;
        d3[2048 + c + j] = hb;
      }
      *(u16x4*)(outall_t + (size_t)b * 1024 + c) = ob;
    }
    if (tid == 0)
      __hip_atomic_store(cnt + tile, 0u, __ATOMIC_RELAXED,
                         __HIP_MEMORY_SCOPE_AGENT);
  }
}

// ---------------------------------------------------------------------------
// prologue helpers
// ---------------------------------------------------------------------------
__global__ __launch_bounds__(256) void cvt_bf16_vec(
    const float* __restrict__ in, u16* __restrict__ out, int n4) {
  int i = blockIdx.x * 256 + threadIdx.x;
  const int stride = gridDim.x * 256;
  for (; i < n4; i += stride) {
    f32x4 v = ((const f32x4*)in)[i];
    u16x4 o;
    o[0] = f2bf(v[0]); o[1] = f2bf(v[1]); o[2] = f2bf(v[2]); o[3] = f2bf(v[3]);
    ((u16x4*)out)[i] = o;
  }
}

__global__ __launch_bounds__(256) void split3_w4(
    const float* __restrict__ W0ih, const float* __restrict__ W0hh,
    const float* __restrict__ W1ih, const float* __restrict__ W1hh,
    u16* __restrict__ W0ihO3, u16* __restrict__ W0hh3,
    u16* __restrict__ W1ih3, u16* __restrict__ W1hh3) {
  const int g = blockIdx.y;
  const int idx = blockIdx.x * 256 + threadIdx.x;  // 3145728
  const int r = idx >> 10, c = idx & 1023;
  const float* src;
  int ld, ofs;
  u16* dst;
  if (g == 0) { src = W0ih; ld = 1600; ofs = 576; dst = W0ihO3; }
  else if (g == 1) { src = W0hh; ld = 1024; ofs = 0; dst = W0hh3; }
  else if (g == 2) { src = W1ih; ld = 1024; ofs = 0; dst = W1ih3; }
  else { src = W1hh; ld = 1024; ofs = 0; dst = W1hh3; }
  const float x = src[(size_t)r * ld + ofs + c];
  const u16 hi = f2bf(x);
  const u16 lo = f2bf(x - bf2f(hi));
  u16* d = dst + (size_t)r * 3072;
  d[c] = hi;
  d[1024 + c] = hi;
  d[2048 + c] = lo;
}

template <bool BSIDE>
__global__ __launch_bounds__(256) void split3(
    const float* __restrict__ src, int src_ld, int src_ofs,
    u16* __restrict__ dst, int C, int total) {
  const int idx = blockIdx.x * 256 + threadIdx.x;
  if (idx >= total) return;
  const int r = idx / C, c = idx - r * C;
  const float x = src[(size_t)r * src_ld + src_ofs + c];
  const u16 hi = f2bf(x);
  const u16 lo = f2bf(x - bf2f(hi));
  u16* d = dst + (size_t)r * (3 * C);
  d[c] = hi;
  d[C + c] = BSIDE ? hi : lo;
  d[2 * C + c] = BSIDE ? lo : hi;
}

__global__ __launch_bounds__(256) void transpose_split3(
    const float* __restrict__ Wa, u16* __restrict__ dst) {
  const int idx = blockIdx.x * 256 + threadIdx.x;
  const int i = idx >> 10, j = idx & 1023;
  const float x = Wa[idx];
  const u16 hi = f2bf(x);
  const u16 lo = f2bf(x - bf2f(hi));
  u16* d = dst + (size_t)j * 3072;
  d[i] = hi;
  d[1024 + i] = hi;
  d[2048 + i] = lo;
}

__global__ __launch_bounds__(256) void gather_emb(
    const int* __restrict__ wid, const int* __restrict__ fid,
    const float* __restrict__ wtab, const float* __restrict__ ftab,
    u16* __restrict__ Xwf) {
  const int r = blockIdx.x;
  const int w = wid[r], f = fid[r];
  u16* dst = Xwf + (size_t)r * 576;
  const float* wsrc = wtab + (size_t)w * 512;
  const float* fsrc = ftab + (size_t)f * 64;
  for (int c = threadIdx.x; c < 512; c += 256) dst[c] = f2bf(wsrc[c]);
  if (threadIdx.x < 64) dst[512 + threadIdx.x] = f2bf(fsrc[threadIdx.x]);
}

DEVFN void trip_store(u16* base3, int c, float x) {
  const u16 hi = f2bf(x);
  const u16 lo = f2bf(x - bf2f(hi));
  base3[c] = hi;
  base3[1024 + c] = lo;
  base3[2048 + c] = hi;
}

__global__ __launch_bounds__(256) void init_state(
    const float* __restrict__ hidden, const float* __restrict__ prev_out,
    float* __restrict__ h0f, float* __restrict__ h1f,
    u16* __restrict__ h0a3, u16* __restrict__ h1a3, u16* __restrict__ out3) {
  const int i = blockIdx.x * 256 + threadIdx.x;
  const int b = i >> 10, c = i & 1023;
  const float aa = hidden[i], bb = hidden[131072 + i], po = prev_out[i];
  h0f[i] = aa;
  h1f[i] = bb;
  trip_store(h0a3 + (size_t)b * 3072, c, aa);
  trip_store(h1a3 + (size_t)b * 3072, c, bb);
  trip_store(out3 + (size_t)b * 3072, c, po);
}

// ---------------------------------------------------------------------------
// per-step kernels.  Ppart planes: 0-3 P, 4-7 G0h, 8-11 G1h.  G1ip: 0-3.
// ---------------------------------------------------------------------------
__global__ __launch_bounds__(256) void gate0_red(
    const float* __restrict__ Ppart, const u16* __restrict__ gi0_t,
    const float* __restrict__ bhh0, float* __restrict__ h0f,
    u16* __restrict__ h0a3) {
  const int i = blockIdx.x * 256 + threadIdx.x;  // 131072
  const int b = i >> 10, c = i & 1023;
  const size_t r3 = (size_t)b * 3072;
  float pr = 0.f, pz = 0.f, pn = 0.f, qr = 0.f, qz = 0.f, qn = 0.f;
#pragma unroll
  for (int ks = 0; ks < 4; ++ks) {
    const float* P0 = Ppart + (size_t)ks * 393216 + r3;
    const float* P1 = Ppart + (size_t)(4 + ks) * 393216 + r3;
    pr += P0[c]; pz += P0[1024 + c]; pn += P0[2048 + c];
    qr += P1[c]; qz += P1[1024 + c]; qn += P1[2048 + c];
  }
  const u16* gi = gi0_t + r3;
  const float h0 = gru_gate(bf2f(gi[c]) + pr, bf2f(gi[1024 + c]) + pz,
                            bf2f(gi[2048 + c]) + pn, qr + bhh0[c],
                            qz + bhh0[1024 + c], qn + bhh0[2048 + c], h0f[i]);
  h0f[i] = h0;
  const u16 hb = f2bf(h0);
  const u16 lb = f2bf(h0 - bf2f(hb));
  h0a3[r3 + c] = hb;
  h0a3[r3 + 1024 + c] = lb;
  h0a3[r3 + 2048 + c] = hb;
}

__global__ __launch_bounds__(256) void attn_red(
    const float* __restrict__ G1ip, const float* __restrict__ Ppart,
    const float* __restrict__ bih1, const float* __restrict__ bhh1,
    const float* __restrict__ ctxWa, const float* __restrict__ ctxf,
    float* __restrict__ h1f, u16* __restrict__ h1a3, u16* __restrict__ cat3) {
  __shared__ float sh1[1024];
  __shared__ float red[256];
  __shared__ float ssc[64];
  const int b = blockIdx.x;
  const int tid = threadIdx.x;
  const int k = tid * 4;
  const size_t r3 = (size_t)b * 3072;
  const size_t r1 = (size_t)b * 1024;
  u16* catr = cat3 + (size_t)b * 6144;

  {
    f32x4 ir = {0.f, 0.f, 0.f, 0.f}, iz = ir, in_ = ir;
    f32x4 hr = ir, hz = ir, hn = ir;
#pragma unroll
    for (int ks = 0; ks < 4; ++ks) {
      const float* gi = G1ip + (size_t)ks * 393216 + r3;
      const float* gh = Ppart + (size_t)(8 + ks) * 393216 + r3;
      ir += *(const f32x4*)(gi + k);
      iz += *(const f32x4*)(gi + 1024 + k);
      in_ += *(const f32x4*)(gi + 2048 + k);
      hr += *(const f32x4*)(gh + k);
      hz += *(const f32x4*)(gh + 1024 + k);
      hn += *(const f32x4*)(gh + 2048 + k);
    }
    f32x4 bir = *(const f32x4*)(bih1 + k);
    f32x4 biz = *(const f32x4*)(bih1 + 1024 + k);
    f32x4 bin_ = *(const f32x4*)(bih1 + 2048 + k);
    f32x4 bhr = *(const f32x4*)(bhh1 + k);
    f32x4 bhz = *(const f32x4*)(bhh1 + 1024 + k);
    f32x4 bhn = *(const f32x4*)(bhh1 + 2048 + k);
    f32x4 hp = *(const f32x4*)(h1f + r1 + k);
    f32x4 hnew;
    u16x4 hb, lb;
#pragma unroll
    for (int j = 0; j < 4; ++j) {
      hnew[j] = gru_gate(ir[j] + bir[j], iz[j] + biz[j], in_[j] + bin_[j],
                         hr[j] + bhr[j], hz[j] + bhz[j], hn[j] + bhn[j], hp[j]);
      sh1[k + j] = hnew[j];
      hb[j] = f2bf(hnew[j]);
      lb[j] = f2bf(hnew[j] - bf2f(hb[j]));
    }
    *(f32x4*)(h1f + r1 + k) = hnew;
    *(u16x4*)(h1a3 + r3 + k) = hb;
    *(u16x4*)(h1a3 + r3 + 1024 + k) = lb;
    *(u16x4*)(h1a3 + r3 + 2048 + k) = hb;
    *(u16x4*)(catr + 1024 + k) = hb;
    *(u16x4*)(catr + 2048 + 1024 + k) = lb;
    *(u16x4*)(catr + 4096 + 1024 + k) = hb;
  }
  __syncthreads();

  const int s = tid >> 2, part = tid & 3;
  {
    const float* cw = ctxWa + ((size_t)b * 64 + s) * 1024 + part * 256;
    const float* hh = sh1 + part * 256;
    float p = 0.f;
    for (int i = 0; i < 256; i += 4) {
      f32x4 v = *(const f32x4*)(cw + i);
      p += v[0] * hh[i] + v[1] * hh[i + 1] + v[2] * hh[i + 2] +
           v[3] * hh[i + 3];
    }
    red[tid] = p;
  }
  __syncthreads();
  if (part == 0) ssc[s] = red[tid] + red[tid + 1] + red[tid + 2] + red[tid + 3];
  __syncthreads();
  if (tid == 0) {
    float mx = -1e30f;
    for (int i = 0; i < 64; ++i) mx = fmaxf(mx, ssc[i]);
    float sm = 0.f;
    for (int i = 0; i < 64; ++i) {
      float e = expf(ssc[i] - mx);
      ssc[i] = e;
      sm += e;
    }
    const float inv = 1.0f / sm;
    for (int i = 0; i < 64; ++i) ssc[i] *= inv;
  }
  __syncthreads();
  {
    float a0 = 0.f, a1 = 0.f, a2 = 0.f, a3 = 0.f;
    const float* cb = ctxf + (size_t)b * 65536 + k;
    for (int s2 = 0; s2 < 64; ++s2) {
      const float w = ssc[s2];
      f32x4 v = *(const f32x4*)(cb + (size_t)s2 * 1024);
      a0 += w * v[0]; a1 += w * v[1]; a2 += w * v[2]; a3 += w * v[3];
    }
    f32x4 cv{a0, a1, a2, a3};
    u16x4 ch, cl;
#pragma unroll
    for (int j = 0; j < 4; ++j) {
      ch[j] = f2bf(cv[j]);
      cl[j] = f2bf(cv[j] - bf2f(ch[j]));
    }
    *(u16x4*)(catr + k) = ch;
    *(u16x4*)(catr + 2048 + k) = cl;
    *(u16x4*)(catr + 4096 + k) = ch;
  }
}

__global__ __launch_bounds__(256) void final_copy(
    const float* __restrict__ h0f, const float* __restrict__ h1f,
    const float* __restrict__ outf, float* __restrict__ dst) {
  const int i = blockIdx.x * 256 + threadIdx.x;
  if (i < 131072) dst[i] = h0f[i];
  else if (i < 262144) dst[i] = h1f[i - 131072];
  else if (i < 393216) dst[i] = outf[i - 262144];
}

// ---------------------------------------------------------------------------
extern "C" void kernel_launch(void* const* d_in, const int* in_sizes, int n_in,
                              void* d_out, int out_size, void* d_ws,
                              size_t ws_size, hipStream_t stream) {
  (void)in_sizes; (void)n_in; (void)out_size; (void)ws_size;
  const int* word_ids = (const int*)d_in[0];
  const int* field_ids = (const int*)d_in[1];
  const float* hidden = (const float*)d_in[3];
  const float* context = (const float*)d_in[4];
  const float* prev_output = (const float*)d_in[6];
  const float* wtab = (const float*)d_in[7];
  const float* ftab = (const float*)d_in[8];
  const float* W0ih = (const float*)d_in[9];
  const float* W0hh = (const float*)d_in[10];
  const float* b0ih = (const float*)d_in[11];
  const float* b0hh = (const float*)d_in[12];
  const float* W1ih = (const float*)d_in[13];
  const float* W1hh = (const float*)d_in[14];
  const float* b1ih = (const float*)d_in[15];
  const float* b1hh = (const float*)d_in[16];
  const float* Wa = (const float*)d_in[17];
  const float* Wc = (const float*)d_in[18];
  const float* Ww = (const float*)d_in[19];
  const float* bw = (const float*)d_in[20];
  const float* Wf = (const float*)d_in[21];
  const float* bfb = (const float*)d_in[22];

  char* p = (char*)d_ws;
  auto take = [&](size_t bytes) {
    char* r = p;
    p += (bytes + 255) & ~(size_t)255;
    return r;
  };
  u16* W0ih_b = (u16*)take(3072ull * 1600 * 2);
  u16* W0ihO3 = (u16*)take(3072ull * 3072 * 2);
  u16* W0hh3 = (u16*)take(3072ull * 3072 * 2);
  u16* W1ih3 = (u16*)take(3072ull * 3072 * 2);
  u16* W1hh3 = (u16*)take(3072ull * 3072 * 2);
  u16* WaT3 = (u16*)take(1024ull * 3072 * 2);
  u16* Wc3 = (u16*)take(1024ull * 6144 * 2);
  u16* Ww_b = (u16*)take(32000ull * 1024 * 2);
  u16* Wf_b = (u16*)take(512ull * 1024 * 2);
  u16* ctx3 = (u16*)take(8192ull * 3072 * 2);
  float* ctxWa_f = (float*)take(8192ull * 1024 * 4);
  u16* Xwf_b = (u16*)take(4096ull * 576 * 2);
  u16* gi0_all_b = (u16*)take(4096ull * 3072 * 2);
  u16* outall_b = (u16*)take(32ull * 128 * 1024 * 2);
  u16* out3 = (u16*)take(128ull * 3072 * 2);
  float* h0f = (float*)take(128ull * 1024 * 4);
  float* h1f = (float*)take(128ull * 1024 * 4);
  float* outf = (float*)take(128ull * 1024 * 4);
  u16* h0a3 = (u16*)take(128ull * 3072 * 2);
  u16* h1a3 = (u16*)take(128ull * 3072 * 2);
  u16* cat3 = (u16*)take(128ull * 6144 * 2);
  float* Ppart = (float*)take(12ull * 128 * 3072 * 4);   // 0-3 P, 4-7 G0h, 8-11 G1h
  float* G1ip = (float*)take(4ull * 128 * 3072 * 4);     // planes 0-3
  float* Wcpart = (float*)take(16ull * 128 * 1024 * 4);  // planes 0-15
  unsigned* wcCnt = (unsigned*)take(256);                // 32 tile counters

  // counters must start at 0 (ws poisoned 0xAA once; captured memset replays)
  hipMemsetAsync(wcCnt, 0, 256, stream);

  // ---- prologue ---------------------------------------------------------
  cvt_bf16_vec<<<dim3(2048), 256, 0, stream>>>(W0ih, W0ih_b, 4915200 / 4);
  split3_w4<<<dim3(12288, 4), 256, 0, stream>>>(W0ih, W0hh, W1ih, W1hh,
                                                W0ihO3, W0hh3, W1ih3, W1hh3);
  split3<true><<<dim3(8192), 256, 0, stream>>>(Wc, 2048, 0, Wc3, 2048,
                                               2097152);
  split3<false><<<dim3(32768), 256, 0, stream>>>(context, 1024, 0, ctx3, 1024,
                                                 8388608);
  transpose_split3<<<dim3(4096), 256, 0, stream>>>(Wa, WaT3);
  cvt_bf16_vec<<<dim3(2048), 256, 0, stream>>>(Ww, Ww_b, 32768000 / 4);
  cvt_bf16_vec<<<dim3(2048), 256, 0, stream>>>(Wf, Wf_b, 524288 / 4);
  gather_emb<<<dim3(4096), 256, 0, stream>>>(word_ids, field_ids, wtab, ftab,
                                             Xwf_b);
  init_state<<<dim3(512), 256, 0, stream>>>(hidden, prev_output, h0f, h1f,
                                            h0a3, h1a3, out3);

  // gi0_wf[t] = Xwf @ W0ih[:, :576]^T + bih0  (bf16 out, plain)
  {
    GemmB3 a{};
    a.A[0] = Xwf_b; a.B[0] = W0ih_b; a.C[0] = gi0_all_b; a.ldb[0] = 1600;
    gemm_bt<128, 128, 1, true><<<dim3(768, 1), 256, 0, stream>>>(
        a, 576, 3072, 24, 576, b0ih, 0);
  }
  // ctxWa = context @ Wa (split-triple, f32 out)
  {
    GemmB3 a{};
    a.A[0] = ctx3; a.B[0] = WaT3; a.C[0] = ctxWa_f; a.ldb[0] = 3072;
    gemm_bt<128, 128, 0, false><<<dim3(512, 1), 256, 0, stream>>>(
        a, 3072, 1024, 8, 3072, nullptr, 0);
  }
  // seed G0h(0) = h0_init @ W0hh -> Ppart planes 4-7
  {
    GemmP a{};
    a.A[0] = h0a3; a.B[0] = W0hh3; a.C[0] = Ppart + 4ull * 393216;
    gemm_part<128, 64><<<dim3(192, 1), 256, 0, stream>>>(
        a, 3072, 3072, 3072, 48, 4, 12, 128);
  }

  // ---- decode loop: 5 launches/step (out_red fused into Wc GEMM) --------
  for (int t = 0; t < 32; ++t) {
    {
      // GEMM1: {P(t) -> planes 0-3, G1h(t) -> planes 8-11}
      GemmP a{};
      a.A[0] = out3;  a.B[0] = W0ihO3; a.C[0] = Ppart;
      a.A[1] = h1a3;  a.B[1] = W1hh3;  a.C[1] = Ppart + 8ull * 393216;
      gemm_part<128, 64><<<dim3(192, 2), 256, 0, stream>>>(
          a, 3072, 3072, 3072, 48, 4, 12, 128);
    }
    gate0_red<<<dim3(512), 256, 0, stream>>>(
        Ppart, gi0_all_b + (size_t)t * 393216, b0hh, h0f, h0a3);
    {
      // GEMM2: {G1i(t) -> G1ip, G0h(t+1) -> Ppart planes 4-7}
      GemmP a{};
      a.A[0] = h0a3; a.B[0] = W1ih3; a.C[0] = G1ip;
      a.A[1] = h0a3; a.B[1] = W0hh3; a.C[1] = Ppart + 4ull * 393216;
      gemm_part<128, 64><<<dim3(192, 2), 256, 0, stream>>>(
          a, 3072, 3072, 3072, 48, 4, 12, 128);
    }
    attn_red<<<dim3(128), 256, 0, stream>>>(G1ip, Ppart, b1ih, b1hh, ctxWa_f,
                                            context, h1f, h1a3, cat3);
    // GEMM3 + fused out-reduction
    gemm_wc_fused<<<dim3(512), 256, 0, stream>>>(
        cat3, Wc3, Wcpart, wcCnt, outf, outall_b + (size_t)t * 131072, out3);
  }

  // ---- generator (time-chunked tile order + gload_lds staging) ----------
  {
    GemmB3 a{};
    a.A[0] = outall_b; a.B[0] = Ww_b; a.C[0] = d_out; a.ldb[0] = 1024;
    gemm_bt<128, 128, 0, true><<<dim3(8000, 1), 256, 0, stream>>>(
        a, 1024, 32000, 250, 1024, bw, 2);
  }
  {
    GemmB3 a{};
    a.A[0] = outall_b; a.B[0] = Wf_b;
    a.C[0] = (float*)d_out + 131072000ull; a.ldb[0] = 1024;
    gemm_bt<128, 128, 0, true><<<dim3(128, 1), 256, 0, stream>>>(
        a, 1024, 512, 4, 1024, bfb, 0);
  }
  final_copy<<<dim3(1536), 256, 0, stream>>>(
      h0f, h1f, outf, (float*)d_out + 133169152ull);
}

// Round 16
// 2844.815 us; speedup vs baseline: 1.6748x; 1.6748x over previous
//
#include <hip/hip_runtime.h>

// ---------------------------------------------------------------------------
// RNN attention decoder (GRU x2 + general attention + generator), MI355X.
// Round 16 = round 14 verbatim (best measured: 2842 us).
//   r15's last-finisher fusion regressed (+60 us/step): device-scope
//   producer->consumer handoff inside a dispatch costs >=50 us/step on this
//   fabric (3rd confirmation: coop grid.sync, spin barrier, last-finisher).
//   Launch boundaries (~3.5 us) are the cheapest device-wide sync.
// Structure:
//   - decode loop: 6 launches/step, K-split partial GEMMs + reducer kernels.
//   - generator: time-chunked tile order (FETCH 890->305 MB) + gload_lds.
// Precision (verified round 6): split-bf16 hi/lo 3-term K-concat on all
// recurrence/attention GEMMs; plain bf16 generator.
// ---------------------------------------------------------------------------

using u16 = unsigned short;
typedef __attribute__((ext_vector_type(4))) float f32x4;
typedef __attribute__((ext_vector_type(4))) u16 u16x4;
typedef __attribute__((ext_vector_type(8))) u16 u16x8;
typedef __attribute__((ext_vector_type(8))) __bf16 bf16x8;

#define DEVFN static __device__ __forceinline__

DEVFN u16 f2bf(float f) {
  unsigned u = __float_as_uint(f);
  return (u16)((u + 0x7FFFu + ((u >> 16) & 1u)) >> 16);
}
DEVFN float bf2f(u16 h) { return __uint_as_float(((unsigned)h) << 16); }
DEVFN float sigm(float x) { return 1.0f / (1.0f + expf(-x)); }
DEVFN float gru_gate(float ir, float iz, float inn,
                     float hr, float hz, float hn, float hprev) {
  float r = sigm(ir + hr);
  float z = sigm(iz + hz);
  float n = tanhf(inn + r * hn);
  return (1.0f - z) * n + z * hprev;
}

// async global->LDS stage of one [ROWS][64] bf16 tile with XOR-swizzle.
// LDS layout: LDS[row*64 + x*8] = global[row, (x^(row&7))*8 ..+8)
template <int ROWS>
DEVFN void stage_tile(const u16* __restrict__ G, int ldg, int kt, u16* lds,
                      int tid) {
  constexpr int IT = (ROWS * 8) / 256;  // 16B chunks per thread
  const int wvbase = tid & ~63;
#pragma unroll
  for (int i = 0; i < IT; ++i) {
    const int chunk = i * 256 + tid;
    const int row = chunk >> 3, c8 = chunk & 7;
    const int cs = c8 ^ (row & 7);
    const u16* src = G + (size_t)row * ldg + (kt * 64 + cs * 8);
    u16* dst = lds + (size_t)(i * 256 + wvbase) * 8;  // wave-uniform base
    __builtin_amdgcn_global_load_lds(
        (const __attribute__((address_space(1))) void*)src,
        (__attribute__((address_space(3))) void*)dst, 16, 0, 0);
  }
}

// ---------------------------------------------------------------------------
// Full-K GEMM C = A * B^T (prologue / generator).
// mode 0: mt-major (mt = bx/Ntiles).  mode 2: chunked 25-nt x 32-mt.
// ---------------------------------------------------------------------------
struct GemmB3 {
  const u16* A[3];
  const u16* B[3];
  void* C[3];
  int ldb[3];
};

template <int BM, int BN, int OUTMODE, bool BIAS>
__global__ __launch_bounds__(256) void gemm_bt(
    GemmB3 args, int lda, int ldc, int Ntiles, int K,
    const float* __restrict__ bias, int mode) {
  constexpr int MF = BM / 32;
  constexpr int NF = BN / 32;
  __shared__ alignas(16) u16 lsA[BM * 64];
  __shared__ alignas(16) u16 lsB[BN * 64];

  const int g = blockIdx.y;
  const int bx = blockIdx.x;
  int mt, nt;
  if (mode == 2) {
    const int c = bx / 800;  // chunk of 25 nt-panels
    const int r = bx - c * 800;
    mt = r & 31;
    nt = c * 25 + (r >> 5);
  } else {
    mt = bx / Ntiles;
    nt = bx - mt * Ntiles;
  }
  const int tid = threadIdx.x;
  const int lane = tid & 63;
  const int wv = tid >> 6;
  const int wr = wv >> 1, wc = wv & 1;
  const int l15 = lane & 15, l4 = lane >> 4;
  const int ldb = args.ldb[g];
  const u16* __restrict__ Ag = args.A[g] + (size_t)mt * BM * lda;
  const u16* __restrict__ Bg = args.B[g] + (size_t)nt * BN * ldb;

  f32x4 acc[MF][NF];
#pragma unroll
  for (int m = 0; m < MF; ++m)
#pragma unroll
    for (int n = 0; n < NF; ++n) acc[m][n] = f32x4{0.f, 0.f, 0.f, 0.f};

  const int KT = K >> 6;
  for (int kt = 0; kt < KT; ++kt) {
    stage_tile<BM>(Ag, lda, kt, lsA, tid);
    stage_tile<BN>(Bg, ldb, kt, lsB, tid);
    __syncthreads();
#pragma unroll
    for (int ks = 0; ks < 2; ++ks) {
      bf16x8 av[MF], bv[NF];
#pragma unroll
      for (int m = 0; m < MF; ++m) {
        const int row = wr * (BM / 2) + m * 16 + l15;
        const int cc = (ks * 4 + l4) ^ (row & 7);
        av[m] = *reinterpret_cast<const bf16x8*>(lsA + row * 64 + cc * 8);
      }
#pragma unroll
      for (int n = 0; n < NF; ++n) {
        const int row = wc * (BN / 2) + n * 16 + l15;
        const int cc = (ks * 4 + l4) ^ (row & 7);
        bv[n] = *reinterpret_cast<const bf16x8*>(lsB + row * 64 + cc * 8);
      }
#pragma unroll
      for (int m = 0; m < MF; ++m)
#pragma unroll
        for (int n = 0; n < NF; ++n)
          acc[m][n] = __builtin_amdgcn_mfma_f32_16x16x32_bf16(
              av[m], bv[n], acc[m][n], 0, 0, 0);
    }
    __syncthreads();
  }

#pragma unroll
  for (int m = 0; m < MF; ++m) {
    const int grow = mt * BM + wr * (BM / 2) + m * 16 + l4 * 4;
#pragma unroll
    for (int n = 0; n < NF; ++n) {
      const int gcol = nt * BN + wc * (BN / 2) + n * 16 + l15;
      const float bsv = BIAS ? bias[gcol] : 0.f;
#pragma unroll
      for (int j = 0; j < 4; ++j) {
        const float v = acc[m][n][j] + bsv;
        const size_t idx = (size_t)(grow + j) * ldc + gcol;
        if constexpr (OUTMODE == 0) {
          ((float*)args.C[g])[idx] = v;
        } else {
          ((u16*)args.C[g])[idx] = f2bf(v);
        }
      }
    }
  }
}

// ---------------------------------------------------------------------------
// K-split partial GEMM: C[g][plane=ks] = A * B^T over K-slice ks.
// ---------------------------------------------------------------------------
struct GemmP {
  const u16* A[3];
  const u16* B[3];
  float* C[3];
};

template <int BM, int BN>
__global__ __launch_bounds__(256) void gemm_part(
    GemmP args, int lda, int ldb, int N, int Ntiles, int KS, int nkt,
    int Mrows) {
  constexpr int MF = BM / 32;
  constexpr int NF = BN / 32;
  __shared__ alignas(16) u16 lsA[BM * 64];
  __shared__ alignas(16) u16 lsB[BN * 64];

  const int g = blockIdx.y;
  const int bx = blockIdx.x;
  const int tile = bx / KS;
  const int ks = bx - tile * KS;
  const int mt = tile / Ntiles;
  const int nt = tile - mt * Ntiles;
  const int tid = threadIdx.x;
  const int lane = tid & 63;
  const int wv = tid >> 6;
  const int wr = wv >> 1, wc = wv & 1;
  const int l15 = lane & 15, l4 = lane >> 4;
  const u16* __restrict__ Ag = args.A[g] + (size_t)mt * BM * lda;
  const u16* __restrict__ Bg = args.B[g] + (size_t)nt * BN * ldb;
  float* __restrict__ Cg =
      args.C[g] + (size_t)ks * Mrows * N + (size_t)mt * BM * N;

  f32x4 acc[MF][NF];
#pragma unroll
  for (int m = 0; m < MF; ++m)
#pragma unroll
    for (int n = 0; n < NF; ++n) acc[m][n] = f32x4{0.f, 0.f, 0.f, 0.f};

  const int kt0 = ks * nkt;
  for (int kk = 0; kk < nkt; ++kk) {
    const int kt = kt0 + kk;
    stage_tile<BM>(Ag, lda, kt, lsA, tid);
    stage_tile<BN>(Bg, ldb, kt, lsB, tid);
    __syncthreads();
#pragma unroll
    for (int k2 = 0; k2 < 2; ++k2) {
      bf16x8 av[MF], bv[NF];
#pragma unroll
      for (int m = 0; m < MF; ++m) {
        const int row = wr * (BM / 2) + m * 16 + l15;
        const int cc = (k2 * 4 + l4) ^ (row & 7);
        av[m] = *reinterpret_cast<const bf16x8*>(lsA + row * 64 + cc * 8);
      }
#pragma unroll
      for (int n = 0; n < NF; ++n) {
        const int row = wc * (BN / 2) + n * 16 + l15;
        const int cc = (k2 * 4 + l4) ^ (row & 7);
        bv[n] = *reinterpret_cast<const bf16x8*>(lsB + row * 64 + cc * 8);
      }
#pragma unroll
      for (int m = 0; m < MF; ++m)
#pragma unroll
        for (int n = 0; n < NF; ++n)
          acc[m][n] = __builtin_amdgcn_mfma_f32_16x16x32_bf16(
              av[m], bv[n], acc[m][n], 0, 0, 0);
    }
    __syncthreads();
  }

#pragma unroll
  for (int m = 0; m < MF; ++m) {
    const int row = wr * (BM / 2) + m * 16 + l4 * 4;
#pragma unroll
    for (int n = 0; n < NF; ++n) {
      const int col = nt * BN + wc * (BN / 2) + n * 16 + l15;
#pragma unroll
      for (int j = 0; j < 4; ++j)
        Cg[(size_t)(row + j) * N + col] = acc[m][n][j];
    }
  }
}

// ---------------------------------------------------------------------------
// prologue helpers
// ---------------------------------------------------------------------------
__global__ __launch_bounds__(256) void cvt_bf16_vec(
    const float* __restrict__ in, u16* __restrict__ out, int n4) {
  int i = blockIdx.x * 256 + threadIdx.x;
  const int stride = gridDim.x * 256;
  for (; i < n4; i += stride) {
    f32x4 v = ((const f32x4*)in)[i];
    u16x4 o;
    o[0] = f2bf(v[0]); o[1] = f2bf(v[1]); o[2] = f2bf(v[2]); o[3] = f2bf(v[3]);
    ((u16x4*)out)[i] = o;
  }
}

__global__ __launch_bounds__(256) void split3_w4(
    const float* __restrict__ W0ih, const float* __restrict__ W0hh,
    const float* __restrict__ W1ih, const float* __restrict__ W1hh,
    u16* __restrict__ W0ihO3, u16* __restrict__ W0hh3,
    u16* __restrict__ W1ih3, u16* __restrict__ W1hh3) {
  const int g = blockIdx.y;
  const int idx = blockIdx.x * 256 + threadIdx.x;  // 3145728
  const int r = idx >> 10, c = idx & 1023;
  const float* src;
  int ld, ofs;
  u16* dst;
  if (g == 0) { src = W0ih; ld = 1600; ofs = 576; dst = W0ihO3; }
  else if (g == 1) { src = W0hh; ld = 1024; ofs = 0; dst = W0hh3; }
  else if (g == 2) { src = W1ih; ld = 1024; ofs = 0; dst = W1ih3; }
  else { src = W1hh; ld = 1024; ofs = 0; dst = W1hh3; }
  const float x = src[(size_t)r * ld + ofs + c];
  const u16 hi = f2bf(x);
  const u16 lo = f2bf(x - bf2f(hi));
  u16* d = dst + (size_t)r * 3072;
  d[c] = hi;
  d[1024 + c] = hi;
  d[2048 + c] = lo;
}

template <bool BSIDE>
__global__ __launch_bounds__(256) void split3(
    const float* __restrict__ src, int src_ld, int src_ofs,
    u16* __restrict__ dst, int C, int total) {
  const int idx = blockIdx.x * 256 + threadIdx.x;
  if (idx >= total) return;
  const int r = idx / C, c = idx - r * C;
  const float x = src[(size_t)r * src_ld + src_ofs + c];
  const u16 hi = f2bf(x);
  const u16 lo = f2bf(x - bf2f(hi));
  u16* d = dst + (size_t)r * (3 * C);
  d[c] = hi;
  d[C + c] = BSIDE ? hi : lo;
  d[2 * C + c] = BSIDE ? lo : hi;
}

__global__ __launch_bounds__(256) void transpose_split3(
    const float* __restrict__ Wa, u16* __restrict__ dst) {
  const int idx = blockIdx.x * 256 + threadIdx.x;
  const int i = idx >> 10, j = idx & 1023;
  const float x = Wa[idx];
  const u16 hi = f2bf(x);
  const u16 lo = f2bf(x - bf2f(hi));
  u16* d = dst + (size_t)j * 3072;
  d[i] = hi;
  d[1024 + i] = hi;
  d[2048 + i] = lo;
}

__global__ __launch_bounds__(256) void gather_emb(
    const int* __restrict__ wid, const int* __restrict__ fid,
    const float* __restrict__ wtab, const float* __restrict__ ftab,
    u16* __restrict__ Xwf) {
  const int r = blockIdx.x;
  const int w = wid[r], f = fid[r];
  u16* dst = Xwf + (size_t)r * 576;
  const float* wsrc = wtab + (size_t)w * 512;
  const float* fsrc = ftab + (size_t)f * 64;
  for (int c = threadIdx.x; c < 512; c += 256) dst[c] = f2bf(wsrc[c]);
  if (threadIdx.x < 64) dst[512 + threadIdx.x] = f2bf(fsrc[threadIdx.x]);
}

DEVFN void trip_store(u16* base3, int c, float x) {
  const u16 hi = f2bf(x);
  const u16 lo = f2bf(x - bf2f(hi));
  base3[c] = hi;
  base3[1024 + c] = lo;
  base3[2048 + c] = hi;
}

__global__ __launch_bounds__(256) void init_state(
    const float* __restrict__ hidden, const float* __restrict__ prev_out,
    float* __restrict__ h0f, float* __restrict__ h1f,
    u16* __restrict__ h0a3, u16* __restrict__ h1a3, u16* __restrict__ out3) {
  const int i = blockIdx.x * 256 + threadIdx.x;
  const int b = i >> 10, c = i & 1023;
  const float aa = hidden[i], bb = hidden[131072 + i], po = prev_out[i];
  h0f[i] = aa;
  h1f[i] = bb;
  trip_store(h0a3 + (size_t)b * 3072, c, aa);
  trip_store(h1a3 + (size_t)b * 3072, c, bb);
  trip_store(out3 + (size_t)b * 3072, c, po);
}

// ---------------------------------------------------------------------------
// per-step kernels.  Ppart planes: 0-3 P, 4-7 G0h, 8-11 G1h.  G1ip: 0-3.
// ---------------------------------------------------------------------------
__global__ __launch_bounds__(256) void gate0_red(
    const float* __restrict__ Ppart, const u16* __restrict__ gi0_t,
    const float* __restrict__ bhh0, float* __restrict__ h0f,
    u16* __restrict__ h0a3) {
  const int i = blockIdx.x * 256 + threadIdx.x;  // 131072
  const int b = i >> 10, c = i & 1023;
  const size_t r3 = (size_t)b * 3072;
  float pr = 0.f, pz = 0.f, pn = 0.f, qr = 0.f, qz = 0.f, qn = 0.f;
#pragma unroll
  for (int ks = 0; ks < 4; ++ks) {
    const float* P0 = Ppart + (size_t)ks * 393216 + r3;
    const float* P1 = Ppart + (size_t)(4 + ks) * 393216 + r3;
    pr += P0[c]; pz += P0[1024 + c]; pn += P0[2048 + c];
    qr += P1[c]; qz += P1[1024 + c]; qn += P1[2048 + c];
  }
  const u16* gi = gi0_t + r3;
  const float h0 = gru_gate(bf2f(gi[c]) + pr, bf2f(gi[1024 + c]) + pz,
                            bf2f(gi[2048 + c]) + pn, qr + bhh0[c],
                            qz + bhh0[1024 + c], qn + bhh0[2048 + c], h0f[i]);
  h0f[i] = h0;
  const u16 hb = f2bf(h0);
  const u16 lb = f2bf(h0 - bf2f(hb));
  h0a3[r3 + c] = hb;
  h0a3[r3 + 1024 + c] = lb;
  h0a3[r3 + 2048 + c] = hb;
}

__global__ __launch_bounds__(256) void attn_red(
    const float* __restrict__ G1ip, const float* __restrict__ Ppart,
    const float* __restrict__ bih1, const float* __restrict__ bhh1,
    const float* __restrict__ ctxWa, const float* __restrict__ ctxf,
    float* __restrict__ h1f, u16* __restrict__ h1a3, u16* __restrict__ cat3) {
  __shared__ float sh1[1024];
  __shared__ float red[256];
  __shared__ float ssc[64];
  const int b = blockIdx.x;
  const int tid = threadIdx.x;
  const int k = tid * 4;
  const size_t r3 = (size_t)b * 3072;
  const size_t r1 = (size_t)b * 1024;
  u16* catr = cat3 + (size_t)b * 6144;

  {
    f32x4 ir = {0.f, 0.f, 0.f, 0.f}, iz = ir, in_ = ir;
    f32x4 hr = ir, hz = ir, hn = ir;
#pragma unroll
    for (int ks = 0; ks < 4; ++ks) {
      const float* gi = G1ip + (size_t)ks * 393216 + r3;
      const float* gh = Ppart + (size_t)(8 + ks) * 393216 + r3;
      ir += *(const f32x4*)(gi + k);
      iz += *(const f32x4*)(gi + 1024 + k);
      in_ += *(const f32x4*)(gi + 2048 + k);
      hr += *(const f32x4*)(gh + k);
      hz += *(const f32x4*)(gh + 1024 + k);
      hn += *(const f32x4*)(gh + 2048 + k);
    }
    f32x4 bir = *(const f32x4*)(bih1 + k);
    f32x4 biz = *(const f32x4*)(bih1 + 1024 + k);
    f32x4 bin_ = *(const f32x4*)(bih1 + 2048 + k);
    f32x4 bhr = *(const f32x4*)(bhh1 + k);
    f32x4 bhz = *(const f32x4*)(bhh1 + 1024 + k);
    f32x4 bhn = *(const f32x4*)(bhh1 + 2048 + k);
    f32x4 hp = *(const f32x4*)(h1f + r1 + k);
    f32x4 hnew;
    u16x4 hb, lb;
#pragma unroll
    for (int j = 0; j < 4; ++j) {
      hnew[j] = gru_gate(ir[j] + bir[j], iz[j] + biz[j], in_[j] + bin_[j],
                         hr[j] + bhr[j], hz[j] + bhz[j], hn[j] + bhn[j], hp[j]);
      sh1[k + j] = hnew[j];
      hb[j] = f2bf(hnew[j]);
      lb[j] = f2bf(hnew[j] - bf2f(hb[j]));
    }
    *(f32x4*)(h1f + r1 + k) = hnew;
    *(u16x4*)(h1a3 + r3 + k) = hb;
    *(u16x4*)(h1a3 + r3 + 1024 + k) = lb;
    *(u16x4*)(h1a3 + r3 + 2048 + k) = hb;
    *(u16x4*)(catr + 1024 + k) = hb;
    *(u16x4*)(catr + 2048 + 1024 + k) = lb;
    *(u16x4*)(catr + 4096 + 1024 + k) = hb;
  }
  __syncthreads();

  const int s = tid >> 2, part = tid & 3;
  {
    const float* cw = ctxWa + ((size_t)b * 64 + s) * 1024 + part * 256;
    const float* hh = sh1 + part * 256;
    float p = 0.f;
    for (int i = 0; i < 256; i += 4) {
      f32x4 v = *(const f32x4*)(cw + i);
      p += v[0] * hh[i] + v[1] * hh[i + 1] + v[2] * hh[i + 2] +
           v[3] * hh[i + 3];
    }
    red[tid] = p;
  }
  __syncthreads();
  if (part == 0) ssc[s] = red[tid] + red[tid + 1] + red[tid + 2] + red[tid + 3];
  __syncthreads();
  if (tid == 0) {
    float mx = -1e30f;
    for (int i = 0; i < 64; ++i) mx = fmaxf(mx, ssc[i]);
    float sm = 0.f;
    for (int i = 0; i < 64; ++i) {
      float e = expf(ssc[i] - mx);
      ssc[i] = e;
      sm += e;
    }
    const float inv = 1.0f / sm;
    for (int i = 0; i < 64; ++i) ssc[i] *= inv;
  }
  __syncthreads();
  {
    float a0 = 0.f, a1 = 0.f, a2 = 0.f, a3 = 0.f;
    const float* cb = ctxf + (size_t)b * 65536 + k;
    for (int s2 = 0; s2 < 64; ++s2) {
      const float w = ssc[s2];
      f32x4 v = *(const f32x4*)(cb + (size_t)s2 * 1024);
      a0 += w * v[0]; a1 += w * v[1]; a2 += w * v[2]; a3 += w * v[3];
    }
    f32x4 cv{a0, a1, a2, a3};
    u16x4 ch, cl;
#pragma unroll
    for (int j = 0; j < 4; ++j) {
      ch[j] = f2bf(cv[j]);
      cl[j] = f2bf(cv[j] - bf2f(ch[j]));
    }
    *(u16x4*)(catr + k) = ch;
    *(u16x4*)(catr + 2048 + k) = cl;
    *(u16x4*)(catr + 4096 + k) = ch;
  }
}

__global__ __launch_bounds__(256) void out_red(
    const float* __restrict__ Wcpart, float* __restrict__ outf,
    u16* __restrict__ outall_t, u16* __restrict__ out3) {
  const int i = blockIdx.x * 256 + threadIdx.x;  // 131072
  const int b = i >> 10, c = i & 1023;
  float v = 0.f;
#pragma unroll
  for (int ks = 0; ks < 16; ++ks) v += Wcpart[(size_t)ks * 131072 + i];
  const float o = tanhf(v);
  outf[i] = o;
  outall_t[i] = f2bf(o);
  const u16 hb = f2bf(o);
  const u16 lb = f2bf(o - bf2f(hb));
  u16* d = out3 + (size_t)b * 3072;
  d[c] = hb;
  d[1024 + c] = lb;
  d[2048 + c] = hb;
}

__global__ __launch_bounds__(256) void final_copy(
    const float* __restrict__ h0f, const float* __restrict__ h1f,
    const float* __restrict__ outf, float* __restrict__ dst) {
  const int i = blockIdx.x * 256 + threadIdx.x;
  if (i < 131072) dst[i] = h0f[i];
  else if (i < 262144) dst[i] = h1f[i - 131072];
  else if (i < 393216) dst[i] = outf[i - 262144];
}

// ---------------------------------------------------------------------------
extern "C" void kernel_launch(void* const* d_in, const int* in_sizes, int n_in,
                              void* d_out, int out_size, void* d_ws,
                              size_t ws_size, hipStream_t stream) {
  (void)in_sizes; (void)n_in; (void)out_size; (void)ws_size;
  const int* word_ids = (const int*)d_in[0];
  const int* field_ids = (const int*)d_in[1];
  const float* hidden = (const float*)d_in[3];
  const float* context = (const float*)d_in[4];
  const float* prev_output = (const float*)d_in[6];
  const float* wtab = (const float*)d_in[7];
  const float* ftab = (const float*)d_in[8];
  const float* W0ih = (const float*)d_in[9];
  const float* W0hh = (const float*)d_in[10];
  const float* b0ih = (const float*)d_in[11];
  const float* b0hh = (const float*)d_in[12];
  const float* W1ih = (const float*)d_in[13];
  const float* W1hh = (const float*)d_in[14];
  const float* b1ih = (const float*)d_in[15];
  const float* b1hh = (const float*)d_in[16];
  const float* Wa = (const float*)d_in[17];
  const float* Wc = (const float*)d_in[18];
  const float* Ww = (const float*)d_in[19];
  const float* bw = (const float*)d_in[20];
  const float* Wf = (const float*)d_in[21];
  const float* bfb = (const float*)d_in[22];

  char* p = (char*)d_ws;
  auto take = [&](size_t bytes) {
    char* r = p;
    p += (bytes + 255) & ~(size_t)255;
    return r;
  };
  u16* W0ih_b = (u16*)take(3072ull * 1600 * 2);
  u16* W0ihO3 = (u16*)take(3072ull * 3072 * 2);
  u16* W0hh3 = (u16*)take(3072ull * 3072 * 2);
  u16* W1ih3 = (u16*)take(3072ull * 3072 * 2);
  u16* W1hh3 = (u16*)take(3072ull * 3072 * 2);
  u16* WaT3 = (u16*)take(1024ull * 3072 * 2);
  u16* Wc3 = (u16*)take(1024ull * 6144 * 2);
  u16* Ww_b = (u16*)take(32000ull * 1024 * 2);
  u16* Wf_b = (u16*)take(512ull * 1024 * 2);
  u16* ctx3 = (u16*)take(8192ull * 3072 * 2);
  float* ctxWa_f = (float*)take(8192ull * 1024 * 4);
  u16* Xwf_b = (u16*)take(4096ull * 576 * 2);
  u16* gi0_all_b = (u16*)take(4096ull * 3072 * 2);
  u16* outall_b = (u16*)take(32ull * 128 * 1024 * 2);
  u16* out3 = (u16*)take(128ull * 3072 * 2);
  float* h0f = (float*)take(128ull * 1024 * 4);
  float* h1f = (float*)take(128ull * 1024 * 4);
  float* outf = (float*)take(128ull * 1024 * 4);
  u16* h0a3 = (u16*)take(128ull * 3072 * 2);
  u16* h1a3 = (u16*)take(128ull * 3072 * 2);
  u16* cat3 = (u16*)take(128ull * 6144 * 2);
  float* Ppart = (float*)take(12ull * 128 * 3072 * 4);   // 0-3 P, 4-7 G0h, 8-11 G1h
  float* G1ip = (float*)take(4ull * 128 * 3072 * 4);     // planes 0-3
  float* Wcpart = (float*)take(16ull * 128 * 1024 * 4);  // planes 0-15

  // ---- prologue ---------------------------------------------------------
  cvt_bf16_vec<<<dim3(2048), 256, 0, stream>>>(W0ih, W0ih_b, 4915200 / 4);
  split3_w4<<<dim3(12288, 4), 256, 0, stream>>>(W0ih, W0hh, W1ih, W1hh,
                                                W0ihO3, W0hh3, W1ih3, W1hh3);
  split3<true><<<dim3(8192), 256, 0, stream>>>(Wc, 2048, 0, Wc3, 2048,
                                               2097152);
  split3<false><<<dim3(32768), 256, 0, stream>>>(context, 1024, 0, ctx3, 1024,
                                                 8388608);
  transpose_split3<<<dim3(4096), 256, 0, stream>>>(Wa, WaT3);
  cvt_bf16_vec<<<dim3(2048), 256, 0, stream>>>(Ww, Ww_b, 32768000 / 4);
  cvt_bf16_vec<<<dim3(2048), 256, 0, stream>>>(Wf, Wf_b, 524288 / 4);
  gather_emb<<<dim3(4096), 256, 0, stream>>>(word_ids, field_ids, wtab, ftab,
                                             Xwf_b);
  init_state<<<dim3(512), 256, 0, stream>>>(hidden, prev_output, h0f, h1f,
                                            h0a3, h1a3, out3);

  // gi0_wf[t] = Xwf @ W0ih[:, :576]^T + bih0  (bf16 out, plain)
  {
    GemmB3 a{};
    a.A[0] = Xwf_b; a.B[0] = W0ih_b; a.C[0] = gi0_all_b; a.ldb[0] = 1600;
    gemm_bt<128, 128, 1, true><<<dim3(768, 1), 256, 0, stream>>>(
        a, 576, 3072, 24, 576, b0ih, 0);
  }
  // ctxWa = context @ Wa (split-triple, f32 out)
  {
    GemmB3 a{};
    a.A[0] = ctx3; a.B[0] = WaT3; a.C[0] = ctxWa_f; a.ldb[0] = 3072;
    gemm_bt<128, 128, 0, false><<<dim3(512, 1), 256, 0, stream>>>(
        a, 3072, 1024, 8, 3072, nullptr, 0);
  }
  // seed G0h(0) = h0_init @ W0hh -> Ppart planes 4-7
  {
    GemmP a{};
    a.A[0] = h0a3; a.B[0] = W0hh3; a.C[0] = Ppart + 4ull * 393216;
    gemm_part<128, 64><<<dim3(192, 1), 256, 0, stream>>>(
        a, 3072, 3072, 3072, 48, 4, 12, 128);
  }

  // ---- decode loop: 6 launches/step, KS=4 on 3072-K GEMMs ---------------
  for (int t = 0; t < 32; ++t) {
    {
      // GEMM1: {P(t) -> planes 0-3, G1h(t) -> planes 8-11}
      GemmP a{};
      a.A[0] = out3;  a.B[0] = W0ihO3; a.C[0] = Ppart;
      a.A[1] = h1a3;  a.B[1] = W1hh3;  a.C[1] = Ppart + 8ull * 393216;
      gemm_part<128, 64><<<dim3(192, 2), 256, 0, stream>>>(
          a, 3072, 3072, 3072, 48, 4, 12, 128);
    }
    gate0_red<<<dim3(512), 256, 0, stream>>>(
        Ppart, gi0_all_b + (size_t)t * 393216, b0hh, h0f, h0a3);
    {
      // GEMM2: {G1i(t) -> G1ip, G0h(t+1) -> Ppart planes 4-7}
      GemmP a{};
      a.A[0] = h0a3; a.B[0] = W1ih3; a.C[0] = G1ip;
      a.A[1] = h0a3; a.B[1] = W0hh3; a.C[1] = Ppart + 4ull * 393216;
      gemm_part<128, 64><<<dim3(192, 2), 256, 0, stream>>>(
          a, 3072, 3072, 3072, 48, 4, 12, 128);
    }
    attn_red<<<dim3(128), 256, 0, stream>>>(G1ip, Ppart, b1ih, b1hh, ctxWa_f,
                                            context, h1f, h1a3, cat3);
    {
      // GEMM3: Wc(t), tiles 2x16, Ksplit16, K=6144
      GemmP a{};
      a.A[0] = cat3; a.B[0] = Wc3; a.C[0] = Wcpart;
      gemm_part<64, 64><<<dim3(512, 1), 256, 0, stream>>>(
          a, 6144, 6144, 1024, 16, 16, 6, 128);
    }
    out_red<<<dim3(512), 256, 0, stream>>>(
        Wcpart, outf, outall_b + (size_t)t * 131072, out3);
  }

  // ---- generator (time-chunked tile order + gload_lds staging) ----------
  {
    GemmB3 a{};
    a.A[0] = outall_b; a.B[0] = Ww_b; a.C[0] = d_out; a.ldb[0] = 1024;
    gemm_bt<128, 128, 0, true><<<dim3(8000, 1), 256, 0, stream>>>(
        a, 1024, 32000, 250, 1024, bw, 2);
  }
  {
    GemmB3 a{};
    a.A[0] = outall_b; a.B[0] = Wf_b;
    a.C[0] = (float*)d_out + 131072000ull; a.ldb[0] = 1024;
    gemm_bt<128, 128, 0, true><<<dim3(128, 1), 256, 0, stream>>>(
        a, 1024, 512, 4, 1024, bfb, 0);
  }
  final_copy<<<dim3(1536), 256, 0, stream>>>(
      h0f, h1f, outf, (float*)d_out + 133169152ull);
}